// Round 5
// baseline (238.598 us; speedup 1.0000x reference)
//
#include <hip/hip_runtime.h>

// Problem constants (N,C,H,W) = (8,19,384,384)
#define NCLS 19
#define HW   147456            // 384*384
#define MPIX 1179648           // 8*384*384
#define NB   256               // histogram buckets per class (LDS-resident)
#define TPB  256               // 4 waves/block
#define NBLK 2304              // 9 blocks/CU; 2304*256*2 == MPIX
#define HSZ  (NCLS * NB)       // 4864 histogram words (= 19 * TPB exactly)

// Kernel A: 2 consecutive pixels per thread, float2 I/O.
// Why 2 px: v[19] as float2 = 38 VGPR -> full register residency fits the
// 64-VGPR/8-waves-per-SIMD budget (4-px needed 76 and the compiler silently
// fell back to cache re-reads at VGPR=52..56 in rounds 1/4). 8 resident
// blocks/CU (LDS 8*19456 = 155.6 KB) * 4 waves = 32 waves/CU vs 18 before:
// the r1/r4 profiles showed latency-bound (VALU 13%, HBM 30%, occ 29%).
// hist[c][k] packs cnt low 16 / pos high 16 (block covers 512 px < 65536).
// Flush skip-zero via u64 global atomics (cnt low32, pos high32).
__global__ void __launch_bounds__(TPB, 8) softmax_err_hist(
    const float* __restrict__ logits,
    const int* __restrict__ label,
    float* __restrict__ errs,                       // [C, M]
    unsigned long long* __restrict__ hist64)        // [HSZ] cnt|pos packed
{
    __shared__ unsigned int hist[HSZ];
    const int tid = threadIdx.x;
    const int b = blockIdx.x;

#pragma unroll
    for (int k = 0; k < NCLS; ++k) hist[tid + k * TPB] = 0u;
    __syncthreads();

    const int m = (b * TPB + tid) * 2;        // 2 consecutive pixels, same image
    const int n = m / HW;                     // HW % 2 == 0 -> both px same n
    const int base = m + n * (NCLS - 1) * HW; // float2-aligned (m % 2 == 0)

    const int2 lbl = *(const int2*)(label + m);

    // load fused with running max (round-1-proven schedule)
    float2 v[NCLS];
    float2 mx = make_float2(-1e30f, -1e30f);
#pragma unroll
    for (int c = 0; c < NCLS; ++c) {
        float2 x = *(const float2*)(logits + base + c * HW);
        v[c] = x;
        mx.x = fmaxf(mx.x, x.x);
        mx.y = fmaxf(mx.y, x.y);
    }
    float2 s = make_float2(0.f, 0.f);
#pragma unroll
    for (int c = 0; c < NCLS; ++c) {
        float2 e;
        e.x = __expf(v[c].x - mx.x);
        e.y = __expf(v[c].y - mx.y);
        v[c] = e;
        s.x += e.x; s.y += e.y;
    }
    const float2 inv = make_float2(1.f / s.x, 1.f / s.y);

#pragma unroll
    for (int c = 0; c < NCLS; ++c) {
        float2 p;
        p.x = v[c].x * inv.x;
        p.y = v[c].y * inv.y;
        float2 err;
        err.x = (c == lbl.x) ? (1.0f - p.x) : p.x;
        err.y = (c == lbl.y) ? (1.0f - p.y) : p.y;
        *(float2*)(errs + (size_t)c * MPIX + m) = err;

        int k0 = min(max((int)(err.x * (float)NB), 0), NB - 1);
        int k1 = min(max((int)(err.y * (float)NB), 0), NB - 1);
        atomicAdd(&hist[c * NB + k0], 1u + ((c == lbl.x) ? 65536u : 0u));
        atomicAdd(&hist[c * NB + k1], 1u + ((c == lbl.y) ? 65536u : 0u));
    }
    __syncthreads();

    // skip-zero u64 atomic flush: cnt (16b) -> low32, pos (16b) -> high32
#pragma unroll
    for (int k = 0; k < NCLS; ++k) {
        const int i = tid + k * TPB;
        unsigned int w = hist[i];
        if (w) {
            unsigned long long add =
                (unsigned long long)(w & 0xFFFFu) |
                ((unsigned long long)(w >> 16) << 32);
            atomicAdd(&hist64[i], add);
        }
    }
}

__device__ __forceinline__ double jaccval(unsigned int n, unsigned int p, unsigned int npos)
{
    // J = 1 - (npos - p) / (npos + n - p); define 0/0 -> 0
    unsigned int denom = (npos - p) + n;
    if (denom == 0u) return 0.0;
    return 1.0 - (double)(npos - p) / (double)denom;
}

// Kernel B: one block per class; thread t owns bucket t. Suffix + trapezoid.
__global__ void __launch_bounds__(NB) lovasz_scan(
    const unsigned long long* __restrict__ hist64,
    float* __restrict__ out0)
{
    const int c = blockIdx.x;
    const int t = threadIdx.x;

    __shared__ unsigned int cntS[NB], posS[NB];
    unsigned long long w = hist64[c * NB + t];
    cntS[t] = (unsigned int)(w & 0xFFFFFFFFull);
    posS[t] = (unsigned int)(w >> 32);
    __syncthreads();

    // suffix-exclusive counts (buckets above t) + total positives
    unsigned int N = 0, P = 0, totP = 0;
    for (int u = 0; u < NB; ++u) {
        totP += posS[u];
        if (u > t) { N += cntS[u]; P += posS[u]; }
    }

    double Jprev = jaccval(N, P, totP);
    N += cntS[t]; P += posS[t];
    double Jnew = jaccval(N, P, totP);
    double acc = 0.5 * (Jprev + Jnew);

    __shared__ double red[NB];
    red[t] = acc;
    __syncthreads();
    for (int s2 = NB / 2; s2 > 0; s2 >>= 1) {
        if (t < s2) red[t] += red[t + s2];
        __syncthreads();
    }
    if (t == 0) {
        double loss_c = red[0] / (double)NB;   // × bucket width
        atomicAdd(out0, (float)(loss_c / (double)NCLS));
    }
}

extern "C" void kernel_launch(void* const* d_in, const int* in_sizes, int n_in,
                              void* d_out, int out_size, void* d_ws, size_t ws_size,
                              hipStream_t stream)
{
    const float* logits = (const float*)d_in[0];
    const int*   label  = (const int*)d_in[1];
    float* out = (float*)d_out;

    // ws layout: [hist64 HSZ u64]
    unsigned long long* hist64 = (unsigned long long*)d_ws;

    hipMemsetAsync(d_ws, 0, (size_t)HSZ * sizeof(unsigned long long), stream);
    hipMemsetAsync(d_out, 0, sizeof(float), stream);

    softmax_err_hist<<<NBLK, TPB, 0, stream>>>(logits, label, out + 1, hist64);
    lovasz_scan<<<NCLS, NB, 0, stream>>>(hist64, out);
}

// Round 6
// 197.863 us; speedup vs baseline: 1.2059x; 1.2059x over previous
//
#include <hip/hip_runtime.h>

// Problem constants (N,C,H,W) = (8,19,384,384)
#define NCLS 19
#define HW   147456            // 384*384
#define MPIX 1179648           // 8*384*384
#define NB   256               // histogram buckets per class (LDS-resident)
#define TPB  384               // 6 waves/block
#define NBLK 1536              // 1536*384*2 == MPIX; 6 blocks/CU grid
#define HSZ  (NCLS * NB)       // 4864 histogram words per block
#define RGROUPS 32             // reduce: groups along partial axis
#define RPER  (NBLK / RGROUPS) // 48 partials per group
#define WBLK  (HSZ / 256)      // 19 word-blocks of 256 threads (exact)

// Kernel A: 2 consecutive pixels per thread, float2 I/O.
// Lessons baked in:
//  - r4/r3/r5: u64 global-atomic flush costs 30-50 us (hot-word L2 RMW
//    serialization: ~2M atomics onto 4864 words). REVERTED to r1's proven
//    non-atomic private partial array + separate reduce kernel.
//  - r5: occupancy alone didn't win, but it was poisoned by the atomic flush.
//  - 4px/thread caps the chip at 18 waves/CU (grid-limited). 2px + TPB=384
//    gives 5 resident blocks * 6 waves = 30 waves/CU; v[19] float2 = 38 VGPR
//    fits the 64-VGPR/8-waves-per-SIMD budget -> true register residency
//    (one load, one exp, one mul per element; no hidden reload passes).
// hist[c][k] packs cnt low 16 / pos high 16 (block covers 768 px < 65536).
__global__ void __launch_bounds__(TPB, 8) softmax_err_hist(
    const float* __restrict__ logits,
    const int* __restrict__ label,
    float* __restrict__ errs,              // [C, M]
    unsigned int* __restrict__ partial)    // [NBLK][HSZ]
{
    __shared__ unsigned int hist[HSZ];
    const int tid = threadIdx.x;
    const int b = blockIdx.x;

    for (int i = tid; i < HSZ; i += TPB) hist[i] = 0u;
    __syncthreads();

    const int m = (b * TPB + tid) * 2;        // 2 consecutive pixels, same image
    const int n = m / HW;                     // HW % 2 == 0 -> both px same n
    const int base = m + n * (NCLS - 1) * HW; // float2-aligned (m % 2 == 0)

    const int2 lbl = *(const int2*)(label + m);

    // load fused with running max (r1-proven natural order)
    float2 v[NCLS];
    float2 mx = make_float2(-1e30f, -1e30f);
#pragma unroll
    for (int c = 0; c < NCLS; ++c) {
        float2 x = *(const float2*)(logits + base + c * HW);
        v[c] = x;
        mx.x = fmaxf(mx.x, x.x);
        mx.y = fmaxf(mx.y, x.y);
    }
    float2 s = make_float2(0.f, 0.f);
#pragma unroll
    for (int c = 0; c < NCLS; ++c) {
        float2 e;
        e.x = __expf(v[c].x - mx.x);
        e.y = __expf(v[c].y - mx.y);
        v[c] = e;
        s.x += e.x; s.y += e.y;
    }
    const float2 inv = make_float2(1.f / s.x, 1.f / s.y);

#pragma unroll
    for (int c = 0; c < NCLS; ++c) {
        float2 p;
        p.x = v[c].x * inv.x;
        p.y = v[c].y * inv.y;
        float2 err;
        err.x = (c == lbl.x) ? (1.0f - p.x) : p.x;
        err.y = (c == lbl.y) ? (1.0f - p.y) : p.y;
        *(float2*)(errs + (size_t)c * MPIX + m) = err;

        int k0 = min(max((int)(err.x * (float)NB), 0), NB - 1);
        int k1 = min(max((int)(err.y * (float)NB), 0), NB - 1);
        atomicAdd(&hist[c * NB + k0], 1u + ((c == lbl.x) ? 65536u : 0u));
        atomicAdd(&hist[c * NB + k1], 1u + ((c == lbl.y) ? 65536u : 0u));
    }
    __syncthreads();

    // non-atomic coalesced flush to this block's private slice (r1-proven)
    unsigned int* dst = partial + (size_t)b * HSZ;
    for (int i = tid; i < HSZ; i += TPB) dst[i] = hist[i];
}

// Kernel R: reduce NBLK packed partials -> unpacked u32 cnt32/pos32.
// Identical to r1's proven reduce (same NBLK/HSZ/RPER).
__global__ void __launch_bounds__(256) reduce_hist(
    const unsigned int* __restrict__ partial,   // [NBLK][HSZ]
    unsigned int* __restrict__ cnt32,           // [HSZ]
    unsigned int* __restrict__ pos32)           // [HSZ]
{
    int g = blockIdx.x / WBLK;
    int wb = blockIdx.x % WBLK;
    int i = wb * 256 + threadIdx.x;             // < HSZ always (19*256 == HSZ)

    unsigned int sc = 0, sp = 0;
    const unsigned int* src = partial + (size_t)(g * RPER) * HSZ + i;
#pragma unroll 4
    for (int b = 0; b < RPER; ++b) {
        unsigned int w = src[(size_t)b * HSZ];
        sc += w & 0xFFFFu;
        sp += w >> 16;
    }
    atomicAdd(&cnt32[i], sc);
    atomicAdd(&pos32[i], sp);
}

__device__ __forceinline__ double jaccval(unsigned int n, unsigned int p, unsigned int npos)
{
    // J = 1 - (npos - p) / (npos + n - p); define 0/0 -> 0
    unsigned int denom = (npos - p) + n;
    if (denom == 0u) return 0.0;
    return 1.0 - (double)(npos - p) / (double)denom;
}

// Kernel B: one block per class; thread t owns bucket t. Suffix + trapezoid.
__global__ void __launch_bounds__(NB) lovasz_scan(
    const unsigned int* __restrict__ cnt32,
    const unsigned int* __restrict__ pos32,
    float* __restrict__ out0)
{
    const int c = blockIdx.x;
    const int t = threadIdx.x;

    __shared__ unsigned int cntS[NB], posS[NB];
    cntS[t] = cnt32[c * NB + t];
    posS[t] = pos32[c * NB + t];
    __syncthreads();

    // suffix-exclusive counts (buckets above t) + total positives
    unsigned int N = 0, P = 0, totP = 0;
    for (int u = 0; u < NB; ++u) {
        totP += posS[u];
        if (u > t) { N += cntS[u]; P += posS[u]; }
    }

    double Jprev = jaccval(N, P, totP);
    N += cntS[t]; P += posS[t];
    double Jnew = jaccval(N, P, totP);
    double acc = 0.5 * (Jprev + Jnew);

    __shared__ double red[NB];
    red[t] = acc;
    __syncthreads();
    for (int s2 = NB / 2; s2 > 0; s2 >>= 1) {
        if (t < s2) red[t] += red[t + s2];
        __syncthreads();
    }
    if (t == 0) {
        double loss_c = red[0] / (double)NB;   // × bucket width
        atomicAdd(out0, (float)(loss_c / (double)NCLS));
    }
}

extern "C" void kernel_launch(void* const* d_in, const int* in_sizes, int n_in,
                              void* d_out, int out_size, void* d_ws, size_t ws_size,
                              hipStream_t stream)
{
    const float* logits = (const float*)d_in[0];
    const int*   label  = (const int*)d_in[1];
    float* out = (float*)d_out;

    // ws layout: [cnt32 HSZ][pos32 HSZ][partial NBLK*HSZ]  (~29.9 MB, as r1)
    unsigned int* cnt32   = (unsigned int*)d_ws;
    unsigned int* pos32   = cnt32 + HSZ;
    unsigned int* partial = pos32 + HSZ;

    hipMemsetAsync(d_ws, 0, (size_t)2 * HSZ * sizeof(unsigned int), stream);
    hipMemsetAsync(d_out, 0, sizeof(float), stream);

    softmax_err_hist<<<NBLK, TPB, 0, stream>>>(logits, label, out + 1, partial);
    reduce_hist<<<WBLK * RGROUPS, 256, 0, stream>>>(partial, cnt32, pos32);
    lovasz_scan<<<NCLS, NB, 0, stream>>>(cnt32, pos32, out);
}

// Round 7
// 187.582 us; speedup vs baseline: 1.2720x; 1.0548x over previous
//
#include <hip/hip_runtime.h>

// Problem constants (N,C,H,W) = (8,19,384,384)
#define NCLS 19
#define HW   147456            // 384*384
#define MPIX 1179648           // 8*384*384
#define NB   256               // histogram buckets per class (LDS-resident)
#define TPB  384               // 6 waves/block
#define NBLK 1536              // 1536*384*2 == MPIX
#define HSZ  (NCLS * NB)       // 4864 histogram words per block
#define NREP 32                // global histogram replicas (kills atomic hot-word chains)

// Kernel A: 2 consecutive pixels per thread, float2 I/O (r6-proven structure:
// 30 waves/CU, VGPR=32, v[19] float2 register-resident).
// Flush: skip-zero u64 atomics into replica (blockIdx & 31). r5 measured the
// single-copy atomic flush at +48 us (hot (c,bucket) words serialize 2304
// L2 RMWs); 32 replicas cut the per-word chain to 48 adds (~2 us worst case)
// while eliminating the 29.9 MB partial write + 29.9 MB reduce read.
// hist[c][k] packs cnt low 16 / pos high 16 (block covers 768 px < 65536).
__global__ void __launch_bounds__(TPB, 8) softmax_err_hist(
    const float* __restrict__ logits,
    const int* __restrict__ label,
    float* __restrict__ errs,                      // [C, M]
    unsigned long long* __restrict__ hist64)       // [NREP][HSZ] cnt|pos packed
{
    __shared__ unsigned int hist[HSZ];
    const int tid = threadIdx.x;
    const int b = blockIdx.x;

    for (int i = tid; i < HSZ; i += TPB) hist[i] = 0u;
    __syncthreads();

    const int m = (b * TPB + tid) * 2;        // 2 consecutive pixels, same image
    const int n = m / HW;                     // HW % 2 == 0 -> both px same n
    const int base = m + n * (NCLS - 1) * HW; // float2-aligned (m % 2 == 0)

    const int2 lbl = *(const int2*)(label + m);

    // load fused with running max (r1/r6-proven natural order)
    float2 v[NCLS];
    float2 mx = make_float2(-1e30f, -1e30f);
#pragma unroll
    for (int c = 0; c < NCLS; ++c) {
        float2 x = *(const float2*)(logits + base + c * HW);
        v[c] = x;
        mx.x = fmaxf(mx.x, x.x);
        mx.y = fmaxf(mx.y, x.y);
    }
    float2 s = make_float2(0.f, 0.f);
#pragma unroll
    for (int c = 0; c < NCLS; ++c) {
        float2 e;
        e.x = __expf(v[c].x - mx.x);
        e.y = __expf(v[c].y - mx.y);
        v[c] = e;
        s.x += e.x; s.y += e.y;
    }
    const float2 inv = make_float2(1.f / s.x, 1.f / s.y);

#pragma unroll
    for (int c = 0; c < NCLS; ++c) {
        float2 p;
        p.x = v[c].x * inv.x;
        p.y = v[c].y * inv.y;
        float2 err;
        err.x = (c == lbl.x) ? (1.0f - p.x) : p.x;
        err.y = (c == lbl.y) ? (1.0f - p.y) : p.y;
        *(float2*)(errs + (size_t)c * MPIX + m) = err;

        int k0 = min(max((int)(err.x * (float)NB), 0), NB - 1);
        int k1 = min(max((int)(err.y * (float)NB), 0), NB - 1);
        atomicAdd(&hist[c * NB + k0], 1u + ((c == lbl.x) ? 65536u : 0u));
        atomicAdd(&hist[c * NB + k1], 1u + ((c == lbl.y) ? 65536u : 0u));
    }
    __syncthreads();

    // skip-zero u64 atomic flush into this block's replica:
    // cnt (16b) -> low32, pos (16b) -> high32. ~27% of words nonzero.
    unsigned long long* dst = hist64 + (size_t)(b & (NREP - 1)) * HSZ;
    for (int i = tid; i < HSZ; i += TPB) {
        unsigned int w = hist[i];
        if (w) {
            unsigned long long add =
                (unsigned long long)(w & 0xFFFFu) |
                ((unsigned long long)(w >> 16) << 32);
            atomicAdd(&dst[i], add);
        }
    }
}

__device__ __forceinline__ double jaccval(unsigned int n, unsigned int p, unsigned int npos)
{
    // J = 1 - (npos - p) / (npos + n - p); define 0/0 -> 0
    unsigned int denom = (npos - p) + n;
    if (denom == 0u) return 0.0;
    return 1.0 - (double)(npos - p) / (double)denom;
}

// Kernel B: one block per class; thread t owns bucket t.
// First reduces the 32 replicas (32 u64 loads/thread, 1.25 MB total), then
// the proven suffix + trapezoid scan. Replaces reduce_hist + lovasz_scan.
__global__ void __launch_bounds__(NB) lovasz_scan(
    const unsigned long long* __restrict__ hist64,  // [NREP][HSZ]
    float* __restrict__ out0)
{
    const int c = blockIdx.x;
    const int t = threadIdx.x;

    unsigned long long sum = 0ull;
#pragma unroll
    for (int r = 0; r < NREP; ++r)
        sum += hist64[(size_t)r * HSZ + c * NB + t];

    __shared__ unsigned int cntS[NB], posS[NB];
    cntS[t] = (unsigned int)(sum & 0xFFFFFFFFull);
    posS[t] = (unsigned int)(sum >> 32);
    __syncthreads();

    // suffix-exclusive counts (buckets above t) + total positives
    unsigned int N = 0, P = 0, totP = 0;
    for (int u = 0; u < NB; ++u) {
        totP += posS[u];
        if (u > t) { N += cntS[u]; P += posS[u]; }
    }

    double Jprev = jaccval(N, P, totP);
    N += cntS[t]; P += posS[t];
    double Jnew = jaccval(N, P, totP);
    double acc = 0.5 * (Jprev + Jnew);

    __shared__ double red[NB];
    red[t] = acc;
    __syncthreads();
    for (int s2 = NB / 2; s2 > 0; s2 >>= 1) {
        if (t < s2) red[t] += red[t + s2];
        __syncthreads();
    }
    if (t == 0) {
        double loss_c = red[0] / (double)NB;   // × bucket width
        atomicAdd(out0, (float)(loss_c / (double)NCLS));
    }
}

extern "C" void kernel_launch(void* const* d_in, const int* in_sizes, int n_in,
                              void* d_out, int out_size, void* d_ws, size_t ws_size,
                              hipStream_t stream)
{
    const float* logits = (const float*)d_in[0];
    const int*   label  = (const int*)d_in[1];
    float* out = (float*)d_out;

    // ws layout: [hist64 NREP*HSZ u64] = 1.25 MB
    unsigned long long* hist64 = (unsigned long long*)d_ws;

    hipMemsetAsync(d_ws, 0, (size_t)NREP * HSZ * sizeof(unsigned long long), stream);
    hipMemsetAsync(d_out, 0, sizeof(float), stream);

    softmax_err_hist<<<NBLK, TPB, 0, stream>>>(logits, label, out + 1, hist64);
    lovasz_scan<<<NCLS, NB, 0, stream>>>(hist64, out);
}